// Round 13
// baseline (94.947 us; speedup 1.0000x reference)
//
#include <hip/hip_runtime.h>
#include <hip/hip_bf16.h>
#include <math.h>

// Problem constants (from setup_inputs / reference)
#define CLASSES     5
#define C_DIM       64
#define HW          441            // 21*21
#define B_ANCH      32
#define NSUP        25             // L*S support images
#define NROWS       (B_ANCH*HW)    // 14112 query rows
#define MSUP        (NSUP*HW)      // 11025 support descriptors
#define PER_CLS     (MSUP/CLASSES) // 2205 per class
#define TILE_COLS   32
#define ROW_BYTES   (C_DIM*2)      // 128 B per bf16 descriptor row
#define TILE_BYTES  (TILE_COLS*ROW_BYTES)   // 4 KB
#define PER_CLS_PAD 2304           // 72 tiles of 32
#define NPAD        (PER_CLS_PAD - PER_CLS) // 99 zero-filled pad rows/class
#define QUARTERS    4              // column splits per class (grid.y = 5*4)
#define TILES_PER_Q 18             // 18 tiles of 32 cols = 576 cols/quarter
#define ROWS_PER_BLK 128           // 4 waves x 32 rows (M_rep=2)
#define NBLK_X      ((NROWS + ROWS_PER_BLK - 1) / ROWS_PER_BLK)  // 111

#define NEG_INF  (-1e30f)

typedef __bf16 bf16x8 __attribute__((ext_vector_type(8)));
typedef float  f32x4  __attribute__((ext_vector_type(4)));

// top-3 insert via med3: 3 independent ops; t0 >= t1 >= t2 invariant.
#define TOP3_INS(v, t0, t1, t2) do {                              \
    float _v = (v);                                               \
    float _n0 = fmaxf(_v, (t0));                                  \
    float _n1 = __builtin_amdgcn_fmed3f(_v, (t0), (t1));          \
    float _n2 = __builtin_amdgcn_fmed3f(_v, (t1), (t2));          \
    (t0) = _n0; (t1) = _n1; (t2) = _n2; } while (0)

// Merge two SORTED triples (u desc, v desc) -> u = top-3 of union. 6 ops.
// Field-validated rounds 9-12 (absmax 0).
#define TRIPLE_MERGE(u0, u1, u2, v0, v1, v2) do {                 \
    float _A = fminf((u0), (v0));                                 \
    float _B = fmaxf((u1), (v1));                                 \
    float _E = fmaxf((u2), (v2));                                 \
    float _m0 = fmaxf((u0), (v0));                                \
    float _m1 = __builtin_amdgcn_fmed3f((u0), (v0), _B);          \
    float _m2 = __builtin_amdgcn_fmed3f(_A, _B, _E);              \
    (u0) = _m0; (u1) = _m1; (u2) = _m2; } while (0)

typedef __attribute__((address_space(1))) const void g_void;
typedef __attribute__((address_space(3))) void l_void;
__device__ __forceinline__ void gload_lds16(const void* g, void* l) {
    __builtin_amdgcn_global_load_lds((g_void*)g, (l_void*)l, 16, 0, 0);
}

#define MFMA16(A, B, C) __builtin_amdgcn_mfma_f32_16x16x32_bf16((A), (B), (C), 0, 0, 0)

// ---------------------------------------------------------------------------
// Kernel 1: L2-normalize all rows (support + anchor) into row-major bf16.
// Support -> sb with per-class row stride PER_CLS_PAD; pad rows zero-filled.
// ---------------------------------------------------------------------------
__global__ __launch_bounds__(256) void norm_rows_kernel(
    const float* __restrict__ anchor, const float* __restrict__ support,
    __bf16* __restrict__ qb, __bf16* __restrict__ sb) {
    int r = blockIdx.x * 256 + threadIdx.x;
    const int total_main = MSUP + NROWS;
    if (r >= total_main) {
        int i = r - total_main;                    // pad-row zero fill
        if (i < CLASSES * NPAD) {
            int cls = i / NPAD, ix = PER_CLS + i % NPAD;
            __bf16* op = sb + ((size_t)cls * PER_CLS_PAD + ix) * C_DIM;
            bf16x8 z = {};
            #pragma unroll
            for (int c0 = 0; c0 < C_DIM; c0 += 8) *(bf16x8*)(op + c0) = z;
        }
        return;
    }
    bool isSup = r < MSUP;
    int rc = isSup ? r : r - MSUP;
    const float* in = isSup ? support : anchor;
    int img = rc / HW, p = rc % HW;
    const float* base = in + (size_t)img * C_DIM * HW + p;
    float q[C_DIM];
    float ss = 0.f;
    #pragma unroll
    for (int c = 0; c < C_DIM; ++c) { q[c] = base[c * HW]; ss += q[c] * q[c]; }
    float sc = rsqrtf(ss);
    __bf16* op;
    if (isSup) {
        int cls = rc / PER_CLS, ix = rc - cls * PER_CLS;
        op = sb + ((size_t)cls * PER_CLS_PAD + ix) * C_DIM;
    } else {
        op = qb + (size_t)rc * C_DIM;
    }
    #pragma unroll
    for (int c0 = 0; c0 < C_DIM; c0 += 8) {
        bf16x8 v;
        #pragma unroll
        for (int j = 0; j < 8; ++j) v[j] = (__bf16)(q[c0 + j] * sc);
        *(bf16x8*)(op + c0) = v;
    }
}

// ---------------------------------------------------------------------------
// Wave-PRIVATE scan of one column-quarter: QNT tiles of 32 cols, each staged
// into this wave's own 2 x 4KB LDS double-buffer via global_load_lds
// (fragment-major: pre-permuted global source, linear LDS dest).
// NO barriers anywhere: waves self-pace and drift out of phase, so the
// ds_read / MFMA / TOP3 bursts of different waves interleave across pipes.
// Pipeline: stage 2 tiles ahead; per tile: vmcnt(4) counted wait (tt+1's 4
// loads stay in flight; vmcnt(0) only on the last tile), 4 ds_read_b128,
// lgkmcnt(0)+sched_barrier (buffer free + don't hoist), issue stage(tt+2),
// 8 MFMA (setprio cluster), 48 TOP3.
// TAIL=true: last tile is class cols 2176-2207 (s=0 full, s=1 iff lr<13).
// ---------------------------------------------------------------------------
template<int QNT, bool TAIL>
__device__ __forceinline__ void scan_quarter(
    const char* qbase,            // sbCls + quarter offset (with laneOff folded)
    char* myLds,                  // this wave's 8 KB (2 x 4 KB buffers)
    int lane, int lr,
    const bf16x8 a0[2], const bf16x8 a1[2],
    float t0[2][4], float t1[2][4], float t2[2][4]) {

    auto stage = [&](int buf, int tt) {
        const char* tb = qbase + tt * TILE_BYTES;
        #pragma unroll
        for (int pr = 0; pr < 4; ++pr)
            gload_lds16(tb + (pr >> 1) * 2048 + (pr & 1) * 64,
                        myLds + buf * 4096 + pr * 1024);
    };

    const f32x4 z = {0.f, 0.f, 0.f, 0.f};

    stage(0, 0);
    stage(1, 1);
    #pragma unroll
    for (int tt = 0; tt < QNT; ++tt) {
        // counted wait: tile tt's 4 loads done; tile tt+1's 4 stay in flight
        if (tt < QNT - 1) asm volatile("s_waitcnt vmcnt(4)" ::: "memory");
        else              asm volatile("s_waitcnt vmcnt(0)" ::: "memory");
        const int buf = tt & 1;
        const bf16x8* sm = (const bf16x8*)(myLds + buf * 4096);
        bf16x8 b0 = sm[0 * 64 + lane];   // (s=0,h=0)
        bf16x8 b1 = sm[1 * 64 + lane];   // (s=0,h=1)
        bf16x8 b2 = sm[2 * 64 + lane];   // (s=1,h=0)
        bf16x8 b3 = sm[3 * 64 + lane];   // (s=1,h=1)
        // buffer free once ds_reads complete; don't let anything hoist above
        asm volatile("s_waitcnt lgkmcnt(0)" ::: "memory");
        __builtin_amdgcn_sched_barrier(0);
        if (tt + 2 < QNT) stage(buf, tt + 2);   // issue-early (T14)
        // pure MFMA cluster into 4 independent accumulators
        f32x4 acc0, acc1, acc2, acc3;
        __builtin_amdgcn_s_setprio(1);
        acc0 = MFMA16(a0[0], b0, z); acc0 = MFMA16(a1[0], b1, acc0);
        acc1 = MFMA16(a0[1], b0, z); acc1 = MFMA16(a1[1], b1, acc1);
        acc2 = MFMA16(a0[0], b2, z); acc2 = MFMA16(a1[0], b3, acc2);
        acc3 = MFMA16(a0[1], b2, z); acc3 = MFMA16(a1[1], b3, acc3);
        __builtin_amdgcn_s_setprio(0);
        // TOP3 stream (8 independent chains)
        const bool tail = TAIL && (tt == QNT - 1);
        if (!tail) {
            #pragma unroll
            for (int j = 0; j < 4; ++j) {
                TOP3_INS(acc0[j], t0[0][j], t1[0][j], t2[0][j]);
                TOP3_INS(acc1[j], t0[1][j], t1[1][j], t2[1][j]);
                TOP3_INS(acc2[j], t0[0][j], t1[0][j], t2[0][j]);
                TOP3_INS(acc3[j], t0[1][j], t1[1][j], t2[1][j]);
            }
        } else {
            // class tile 68: s=0 (acc0/acc1) full; s=1 (acc2/acc3) iff lr<13
            bool valid = lr < 13;     // SELECT mask: pads stay out
            #pragma unroll
            for (int j = 0; j < 4; ++j) {
                TOP3_INS(acc0[j], t0[0][j], t1[0][j], t2[0][j]);
                TOP3_INS(acc1[j], t0[1][j], t1[1][j], t2[1][j]);
                float v2 = valid ? acc2[j] : NEG_INF;
                float v3 = valid ? acc3[j] : NEG_INF;
                TOP3_INS(v2, t0[0][j], t1[0][j], t2[0][j]);
                TOP3_INS(v3, t0[1][j], t1[1][j], t2[1][j]);
            }
        }
    }
}

// ---------------------------------------------------------------------------
// Kernel 2: MFMA GEMM + partial top-3 per (row, class, quarter).
// Grid (111, 20), block 256 = 4 fully-independent waves; wave owns 32 rows.
// LDS 32 KB (4 waves x 8 KB private dbuf) -> 5 blocks/CU; no __syncthreads.
// A/B frag: row/col = lane&15, k = (lane>>4)*8+[0..7].
// C/D: col = lane&15, row = (lane>>4)*4 + reg.   (validated rounds 2-12)
// ---------------------------------------------------------------------------
__global__ __launch_bounds__(256, 4) void knn_mfma_kernel(
    const __bf16* __restrict__ qb, const __bf16* __restrict__ sb,
    float* __restrict__ part) {
    __shared__ char smem[4][8192];   // 32 KB: per-wave private double buffers

    int lane = threadIdx.x & 63;
    int w    = threadIdx.x >> 6;           // 0..3
    int lr   = lane & 15;
    int kg   = lane >> 4;
    int cls  = blockIdx.y >> 2;
    int q    = blockIdx.y & 3;
    int rowbase = blockIdx.x * ROWS_PER_BLK + w * 32;

    bf16x8 a0[2], a1[2];
    #pragma unroll
    for (int r = 0; r < 2; ++r) {
        int arow = rowbase + r * 16 + lr;
        int arc  = arow < NROWS ? arow : NROWS - 1;
        const bf16x8* qrow = (const bf16x8*)(qb + (size_t)arc * C_DIM);
        a0[r] = qrow[kg];
        a1[r] = qrow[4 + kg];
    }

    float t0[2][4], t1[2][4], t2[2][4];
    #pragma unroll
    for (int r = 0; r < 2; ++r)
        #pragma unroll
        for (int j = 0; j < 4; ++j) {
            t0[r][j] = NEG_INF; t1[r][j] = NEG_INF; t2[r][j] = NEG_INF;
        }

    // per-lane fragment permutation folded into the global base pointer
    const char* qbase = (const char*)sb
        + (size_t)cls * PER_CLS_PAD * ROW_BYTES
        + (size_t)q * TILES_PER_Q * TILE_BYTES
        + lr * ROW_BYTES + kg * 16;

    if (q == 3)   // tiles 54..68 valid (69..71 all-pad skipped), tail masked
        scan_quarter<15, true >(qbase, smem[w], lane, lr, a0, a1, t0, t1, t2);
    else
        scan_quarter<18, false>(qbase, smem[w], lane, lr, a0, a1, t0, t1, t2);

    // Merge top-3 across the 16 column-lanes per row (sorted-triple butterfly)
    #pragma unroll
    for (int r = 0; r < 2; ++r) {
        #pragma unroll
        for (int j = 0; j < 4; ++j) {
            float u0 = t0[r][j], u1 = t1[r][j], u2 = t2[r][j];
            #pragma unroll
            for (int off = 1; off < 16; off <<= 1) {
                float v0 = __shfl_xor(u0, off, 64);
                float v1 = __shfl_xor(u1, off, 64);
                float v2 = __shfl_xor(u2, off, 64);
                TRIPLE_MERGE(u0, u1, u2, v0, v1, v2);
            }
            int row = rowbase + r * 16 + kg * 4 + j;
            if (lr == 0 && row < NROWS) {
                float* pp = part +
                    ((size_t)(row * CLASSES + cls) * QUARTERS + q) * 3;
                pp[0] = u0; pp[1] = u1; pp[2] = u2;
            }
        }
    }
}

// ---------------------------------------------------------------------------
// Kernel 3: merge quarter partial top-3s, sigmoid, reduce over 441 locations.
// ---------------------------------------------------------------------------
__global__ __launch_bounds__(64) void merge_reduce_kernel(
    const float* __restrict__ part, float* __restrict__ out) {
    int bl = blockIdx.x;
    int b = bl / CLASSES;
    int l = bl % CLASSES;
    int lane = threadIdx.x;
    float acc = 0.f;
    for (int p = lane; p < HW; p += 64) {
        int row = b * HW + p;
        const float* pp = part + (size_t)(row * CLASSES + l) * (QUARTERS * 3);
        float u0 = pp[0], u1 = pp[1], u2 = pp[2];
        TRIPLE_MERGE(u0, u1, u2, pp[3], pp[4],  pp[5]);
        TRIPLE_MERGE(u0, u1, u2, pp[6], pp[7],  pp[8]);
        TRIPLE_MERGE(u0, u1, u2, pp[9], pp[10], pp[11]);
        acc += 1.f / (1.f + __expf(-u0))
             + 1.f / (1.f + __expf(-u1))
             + 1.f / (1.f + __expf(-u2));
    }
    #pragma unroll
    for (int off = 32; off; off >>= 1) acc += __shfl_xor(acc, off, 64);
    if (lane == 0) out[bl] = acc;
}

// ---------------------------------------------------------------------------
extern "C" void kernel_launch(void* const* d_in, const int* in_sizes, int n_in,
                              void* d_out, int out_size, void* d_ws, size_t ws_size,
                              hipStream_t stream) {
    const float* anchor  = (const float*)d_in[0];
    const float* support = (const float*)d_in[1];
    // d_in[2]=av_num(1), d_in[3]=sav_num(1) -- fixed by setup, ignored.

    // ws: sb bf16[5*2304*64] | qb bf16[NROWS*64] | part f32[NROWS*5*4*3]
    __bf16* sb = (__bf16*)d_ws;
    __bf16* qb = sb + (size_t)CLASSES * PER_CLS_PAD * C_DIM;
    float* part = (float*)(qb + (size_t)NROWS * C_DIM);

    {
        int total = MSUP + NROWS + CLASSES * NPAD;
        dim3 g((total + 255) / 256);
        norm_rows_kernel<<<g, 256, 0, stream>>>(anchor, support, qb, sb);
    }
    {
        dim3 g(NBLK_X, CLASSES * QUARTERS);
        knn_mfma_kernel<<<g, 256, 0, stream>>>(qb, sb, part);
    }
    {
        dim3 gm(B_ANCH * CLASSES);
        merge_reduce_kernel<<<gm, 64, 0, stream>>>(part, (float*)d_out);
    }
}

// Round 14
// 56.895 us; speedup vs baseline: 1.6688x; 1.6688x over previous
//
#include <hip/hip_runtime.h>
#include <hip/hip_bf16.h>
#include <math.h>

// Problem constants (from setup_inputs / reference)
#define CLASSES     5
#define C_DIM       64
#define HW          441            // 21*21
#define B_ANCH      32
#define NSUP        25             // L*S support images
#define NROWS       (B_ANCH*HW)    // 14112 query rows
#define MSUP        (NSUP*HW)      // 11025 support descriptors
#define PER_CLS     (MSUP/CLASSES) // 2205 per class
#define TILE_COLS   32
#define ROW_BYTES   (C_DIM*2)      // 128 B per bf16 descriptor row
#define TILE_BYTES  (TILE_COLS*ROW_BYTES)   // 4 KB
#define PER_CLS_PAD 2304           // 72 tiles of 32
#define NPAD        (PER_CLS_PAD - PER_CLS) // 99 zero-filled pad rows/class
#define QUARTERS    4              // column splits per class (grid.y = 5*4)
#define TILES_PER_Q 18             // 18 tiles of 32 cols = 576 cols/quarter
#define ROWS_PER_BLK 128           // 4 waves x 32 rows (M_rep=2)
#define NBLK_X      ((NROWS + ROWS_PER_BLK - 1) / ROWS_PER_BLK)  // 111

#define NEG_INF  (-1e30f)

typedef __bf16 bf16x8 __attribute__((ext_vector_type(8)));
typedef float  f32x4  __attribute__((ext_vector_type(4)));

// top-3 insert via med3: 3 independent ops; t0 >= t1 >= t2 invariant.
#define TOP3_INS(v, t0, t1, t2) do {                              \
    float _v = (v);                                               \
    float _n0 = fmaxf(_v, (t0));                                  \
    float _n1 = __builtin_amdgcn_fmed3f(_v, (t0), (t1));          \
    float _n2 = __builtin_amdgcn_fmed3f(_v, (t1), (t2));          \
    (t0) = _n0; (t1) = _n1; (t2) = _n2; } while (0)

// Merge two SORTED triples (u desc, v desc) -> u = top-3 of union. 6 ops.
// Field-validated rounds 9-13 (absmax 0).
#define TRIPLE_MERGE(u0, u1, u2, v0, v1, v2) do {                 \
    float _A = fminf((u0), (v0));                                 \
    float _B = fmaxf((u1), (v1));                                 \
    float _E = fmaxf((u2), (v2));                                 \
    float _m0 = fmaxf((u0), (v0));                                \
    float _m1 = __builtin_amdgcn_fmed3f((u0), (v0), _B);          \
    float _m2 = __builtin_amdgcn_fmed3f(_A, _B, _E);              \
    (u0) = _m0; (u1) = _m1; (u2) = _m2; } while (0)

typedef __attribute__((address_space(1))) const void g_void;
typedef __attribute__((address_space(3))) void l_void;
__device__ __forceinline__ void gload_lds16(const void* g, void* l) {
    __builtin_amdgcn_global_load_lds((g_void*)g, (l_void*)l, 16, 0, 0);
}

#define MFMA16(A, B, C) __builtin_amdgcn_mfma_f32_16x16x32_bf16((A), (B), (C), 0, 0, 0)

// ---------------------------------------------------------------------------
// Kernel 1: L2-normalize all rows (support + anchor) into row-major bf16.
// Support -> sb with per-class row stride PER_CLS_PAD; pad rows zero-filled.
// ---------------------------------------------------------------------------
__global__ __launch_bounds__(256) void norm_rows_kernel(
    const float* __restrict__ anchor, const float* __restrict__ support,
    __bf16* __restrict__ qb, __bf16* __restrict__ sb) {
    int r = blockIdx.x * 256 + threadIdx.x;
    const int total_main = MSUP + NROWS;
    if (r >= total_main) {
        int i = r - total_main;                    // pad-row zero fill
        if (i < CLASSES * NPAD) {
            int cls = i / NPAD, ix = PER_CLS + i % NPAD;
            __bf16* op = sb + ((size_t)cls * PER_CLS_PAD + ix) * C_DIM;
            bf16x8 z = {};
            #pragma unroll
            for (int c0 = 0; c0 < C_DIM; c0 += 8) *(bf16x8*)(op + c0) = z;
        }
        return;
    }
    bool isSup = r < MSUP;
    int rc = isSup ? r : r - MSUP;
    const float* in = isSup ? support : anchor;
    int img = rc / HW, p = rc % HW;
    const float* base = in + (size_t)img * C_DIM * HW + p;
    float q[C_DIM];
    float ss = 0.f;
    #pragma unroll
    for (int c = 0; c < C_DIM; ++c) { q[c] = base[c * HW]; ss += q[c] * q[c]; }
    float sc = rsqrtf(ss);
    __bf16* op;
    if (isSup) {
        int cls = rc / PER_CLS, ix = rc - cls * PER_CLS;
        op = sb + ((size_t)cls * PER_CLS_PAD + ix) * C_DIM;
    } else {
        op = qb + (size_t)rc * C_DIM;
    }
    #pragma unroll
    for (int c0 = 0; c0 < C_DIM; c0 += 8) {
        bf16x8 v;
        #pragma unroll
        for (int j = 0; j < 8; ++j) v[j] = (__bf16)(q[c0 + j] * sc);
        *(bf16x8*)(op + c0) = v;
    }
}

// ---------------------------------------------------------------------------
// ROLLED GEMM+top3 over one column-quarter (QNT tiles of 32 cols).
// Identical geometry/math to the round-12 kernel (best so far), but the
// K-loop is NOT unrolled: body ~75 instructions (~0.5 KB) instead of a
// ~10 KB fully-unrolled body — tests the I-cache-pressure theory.
// Cooperative staging: each of the 4 waves stages 1 granule/tile (pr = w);
// 3 buffers, stage 2 ahead, counted vmcnt(1) (vmcnt(0) only on last tile).
// Last tile peeled out of the loop (compile-time TAIL mask, no per-iter
// branch). Decoupled streams per tile: 4 ds_read -> 8 MFMA (setprio
// cluster) -> 48 TOP3.
// ---------------------------------------------------------------------------
template<int QNT, bool TAIL>
__device__ __forceinline__ void gemm_quarter(
    const char* qbase,            // sbCls + quarter offset
    char* smem_base,              // 3 x 4KB LDS buffers
    int laneOff,                  // lr*128 + kg*16 (per-lane source permute)
    int pr0, int lane, int lr,
    const bf16x8 a0[2], const bf16x8 a1[2],
    float t0[2][4], float t1[2][4], float t2[2][4]) {

    auto stage = [&](int buf, int tt) {
        const char* tb = qbase + tt * TILE_BYTES;
        gload_lds16(tb + ((pr0 >> 1) * 2048 + (pr0 & 1) * 64) + laneOff,
                    smem_base + buf * 4096 + pr0 * 1024);
    };
    const f32x4 z = {0.f, 0.f, 0.f, 0.f};

    stage(0, 0);
    stage(1, 1);
    int buf = 0;
    #pragma unroll 1
    for (int tt = 0; tt < QNT - 1; ++tt) {
        // tile tt's stage done; tile tt+1's single load stays in flight
        asm volatile("s_waitcnt vmcnt(1)" ::: "memory");
        __builtin_amdgcn_s_barrier();
        if (tt + 2 < QNT) {
            int pbuf = buf + 2; if (pbuf >= 3) pbuf -= 3;
            stage(pbuf, tt + 2);
        }
        const bf16x8* sm = (const bf16x8*)(smem_base + buf * 4096);
        bf16x8 b0 = sm[0 * 64 + lane];
        bf16x8 b1 = sm[1 * 64 + lane];
        bf16x8 b2 = sm[2 * 64 + lane];
        bf16x8 b3 = sm[3 * 64 + lane];
        f32x4 acc0, acc1, acc2, acc3;
        __builtin_amdgcn_s_setprio(1);
        acc0 = MFMA16(a0[0], b0, z); acc0 = MFMA16(a1[0], b1, acc0);
        acc1 = MFMA16(a0[1], b0, z); acc1 = MFMA16(a1[1], b1, acc1);
        acc2 = MFMA16(a0[0], b2, z); acc2 = MFMA16(a1[0], b3, acc2);
        acc3 = MFMA16(a0[1], b2, z); acc3 = MFMA16(a1[1], b3, acc3);
        __builtin_amdgcn_s_setprio(0);
        #pragma unroll
        for (int j = 0; j < 4; ++j) {
            TOP3_INS(acc0[j], t0[0][j], t1[0][j], t2[0][j]);
            TOP3_INS(acc1[j], t0[1][j], t1[1][j], t2[1][j]);
            TOP3_INS(acc2[j], t0[0][j], t1[0][j], t2[0][j]);
            TOP3_INS(acc3[j], t0[1][j], t1[1][j], t2[1][j]);
        }
        buf = (buf + 1 == 3) ? 0 : buf + 1;
    }
    // peeled last tile (tile QNT-1, in buffer (QNT-1)%3 == buf)
    asm volatile("s_waitcnt vmcnt(0)" ::: "memory");
    __builtin_amdgcn_s_barrier();
    {
        const bf16x8* sm = (const bf16x8*)(smem_base + buf * 4096);
        bf16x8 b0 = sm[0 * 64 + lane];
        bf16x8 b1 = sm[1 * 64 + lane];
        bf16x8 b2 = sm[2 * 64 + lane];
        bf16x8 b3 = sm[3 * 64 + lane];
        f32x4 acc0, acc1, acc2, acc3;
        __builtin_amdgcn_s_setprio(1);
        acc0 = MFMA16(a0[0], b0, z); acc0 = MFMA16(a1[0], b1, acc0);
        acc1 = MFMA16(a0[1], b0, z); acc1 = MFMA16(a1[1], b1, acc1);
        acc2 = MFMA16(a0[0], b2, z); acc2 = MFMA16(a1[0], b3, acc2);
        acc3 = MFMA16(a0[1], b2, z); acc3 = MFMA16(a1[1], b3, acc3);
        __builtin_amdgcn_s_setprio(0);
        if (!TAIL) {
            #pragma unroll
            for (int j = 0; j < 4; ++j) {
                TOP3_INS(acc0[j], t0[0][j], t1[0][j], t2[0][j]);
                TOP3_INS(acc1[j], t0[1][j], t1[1][j], t2[1][j]);
                TOP3_INS(acc2[j], t0[0][j], t1[0][j], t2[0][j]);
                TOP3_INS(acc3[j], t0[1][j], t1[1][j], t2[1][j]);
            }
        } else {
            // class tile 68: s=0 (acc0/acc1) full; s=1 (acc2/acc3) iff lr<13
            bool valid = lr < 13;     // SELECT mask: pad rows stay out
            #pragma unroll
            for (int j = 0; j < 4; ++j) {
                TOP3_INS(acc0[j], t0[0][j], t1[0][j], t2[0][j]);
                TOP3_INS(acc1[j], t0[1][j], t1[1][j], t2[1][j]);
                float v2 = valid ? acc2[j] : NEG_INF;
                float v3 = valid ? acc3[j] : NEG_INF;
                TOP3_INS(v2, t0[0][j], t1[0][j], t2[0][j]);
                TOP3_INS(v3, t0[1][j], t1[1][j], t2[1][j]);
            }
        }
    }
}

// ---------------------------------------------------------------------------
// Kernel 2: MFMA GEMM + partial top-3 per (row, class, quarter).
// Grid (111, 20), block 256 = 4 waves; wave owns 32 rows (M_rep=2).
// LDS 12 KB (3 x 4KB); B staged fragment-major (pre-permuted global source,
// linear LDS dest -> conflict-free ds_read_b128); counted vmcnt(1).
// A/B frag: row/col = lane&15, k = (lane>>4)*8+[0..7].
// C/D: col = lane&15, row = (lane>>4)*4 + reg.   (validated rounds 2-13)
// ---------------------------------------------------------------------------
__global__ __launch_bounds__(256, 4) void knn_mfma_kernel(
    const __bf16* __restrict__ qb, const __bf16* __restrict__ sb,
    float* __restrict__ part) {
    __shared__ char smem[3][4096];   // 12 KB

    int lane = threadIdx.x & 63;
    int w    = threadIdx.x >> 6;           // 0..3
    int lr   = lane & 15;
    int kg   = lane >> 4;
    int cls  = blockIdx.y >> 2;
    int q    = blockIdx.y & 3;
    int rowbase = blockIdx.x * ROWS_PER_BLK + w * 32;

    bf16x8 a0[2], a1[2];
    #pragma unroll
    for (int r = 0; r < 2; ++r) {
        int arow = rowbase + r * 16 + lr;
        int arc  = arow < NROWS ? arow : NROWS - 1;
        const bf16x8* qrow = (const bf16x8*)(qb + (size_t)arc * C_DIM);
        a0[r] = qrow[kg];
        a1[r] = qrow[4 + kg];
    }

    float t0[2][4], t1[2][4], t2[2][4];
    #pragma unroll
    for (int r = 0; r < 2; ++r)
        #pragma unroll
        for (int j = 0; j < 4; ++j) {
            t0[r][j] = NEG_INF; t1[r][j] = NEG_INF; t2[r][j] = NEG_INF;
        }

    const char* qbase = (const char*)sb
        + (size_t)cls * PER_CLS_PAD * ROW_BYTES
        + (size_t)q * TILES_PER_Q * TILE_BYTES;
    int laneOff = lr * ROW_BYTES + kg * 16;

    if (q == 3)   // tiles 54..68 valid (69..71 all-pad skipped), tail masked
        gemm_quarter<15, true >(qbase, (char*)smem, laneOff, w, lane, lr,
                                a0, a1, t0, t1, t2);
    else
        gemm_quarter<18, false>(qbase, (char*)smem, laneOff, w, lane, lr,
                                a0, a1, t0, t1, t2);

    // Merge top-3 across the 16 column-lanes per row (sorted-triple butterfly)
    #pragma unroll
    for (int r = 0; r < 2; ++r) {
        #pragma unroll
        for (int j = 0; j < 4; ++j) {
            float u0 = t0[r][j], u1 = t1[r][j], u2 = t2[r][j];
            #pragma unroll
            for (int off = 1; off < 16; off <<= 1) {
                float v0 = __shfl_xor(u0, off, 64);
                float v1 = __shfl_xor(u1, off, 64);
                float v2 = __shfl_xor(u2, off, 64);
                TRIPLE_MERGE(u0, u1, u2, v0, v1, v2);
            }
            int row = rowbase + r * 16 + kg * 4 + j;
            if (lr == 0 && row < NROWS) {
                float* pp = part +
                    ((size_t)(row * CLASSES + cls) * QUARTERS + q) * 3;
                pp[0] = u0; pp[1] = u1; pp[2] = u2;
            }
        }
    }
}

// ---------------------------------------------------------------------------
// Kernel 3: merge quarter partial top-3s, sigmoid, reduce over 441 locations.
// ---------------------------------------------------------------------------
__global__ __launch_bounds__(64) void merge_reduce_kernel(
    const float* __restrict__ part, float* __restrict__ out) {
    int bl = blockIdx.x;
    int b = bl / CLASSES;
    int l = bl % CLASSES;
    int lane = threadIdx.x;
    float acc = 0.f;
    for (int p = lane; p < HW; p += 64) {
        int row = b * HW + p;
        const float* pp = part + (size_t)(row * CLASSES + l) * (QUARTERS * 3);
        float u0 = pp[0], u1 = pp[1], u2 = pp[2];
        TRIPLE_MERGE(u0, u1, u2, pp[3], pp[4],  pp[5]);
        TRIPLE_MERGE(u0, u1, u2, pp[6], pp[7],  pp[8]);
        TRIPLE_MERGE(u0, u1, u2, pp[9], pp[10], pp[11]);
        acc += 1.f / (1.f + __expf(-u0))
             + 1.f / (1.f + __expf(-u1))
             + 1.f / (1.f + __expf(-u2));
    }
    #pragma unroll
    for (int off = 32; off; off >>= 1) acc += __shfl_xor(acc, off, 64);
    if (lane == 0) out[bl] = acc;
}

// ---------------------------------------------------------------------------
extern "C" void kernel_launch(void* const* d_in, const int* in_sizes, int n_in,
                              void* d_out, int out_size, void* d_ws, size_t ws_size,
                              hipStream_t stream) {
    const float* anchor  = (const float*)d_in[0];
    const float* support = (const float*)d_in[1];
    // d_in[2]=av_num(1), d_in[3]=sav_num(1) -- fixed by setup, ignored.

    // ws: sb bf16[5*2304*64] | qb bf16[NROWS*64] | part f32[NROWS*5*4*3]
    __bf16* sb = (__bf16*)d_ws;
    __bf16* qb = sb + (size_t)CLASSES * PER_CLS_PAD * C_DIM;
    float* part = (float*)(qb + (size_t)NROWS * C_DIM);

    {
        int total = MSUP + NROWS + CLASSES * NPAD;
        dim3 g((total + 255) / 256);
        norm_rows_kernel<<<g, 256, 0, stream>>>(anchor, support, qb, sb);
    }
    {
        dim3 g(NBLK_X, CLASSES * QUARTERS);
        knn_mfma_kernel<<<g, 256, 0, stream>>>(qb, sb, part);
    }
    {
        dim3 gm(B_ANCH * CLASSES);
        merge_reduce_kernel<<<gm, 64, 0, stream>>>(part, (float*)d_out);
    }
}

// Round 15
// 53.623 us; speedup vs baseline: 1.7707x; 1.0610x over previous
//
#include <hip/hip_runtime.h>
#include <hip/hip_bf16.h>
#include <math.h>

// Problem constants (from setup_inputs / reference)
#define CLASSES     5
#define C_DIM       64
#define HW          441            // 21*21
#define B_ANCH      32
#define NSUP        25             // L*S support images
#define NROWS       (B_ANCH*HW)    // 14112 query rows
#define MSUP        (NSUP*HW)      // 11025 support descriptors
#define PER_CLS     (MSUP/CLASSES) // 2205 per class
#define TILE_COLS   32
#define ROW_BYTES   (C_DIM*2)      // 128 B per bf16 descriptor row
#define TILE_BYTES  (TILE_COLS*ROW_BYTES)   // 4 KB
#define PER_CLS_PAD 2304           // 72 tiles of 32
#define NPAD        (PER_CLS_PAD - PER_CLS) // 99 zero-filled pad rows/class
#define QUARTERS    4              // column splits per class (grid.y = 5*4)
#define TILES_PER_Q 18             // 18 tiles of 32 cols = 576 cols/quarter
#define ROWS_PER_BLK 128           // 4 waves x 32 rows (M_rep=2)
#define NBLK_X      ((NROWS + ROWS_PER_BLK - 1) / ROWS_PER_BLK)  // 111

#define NEG_INF  (-1e30f)

typedef __bf16 bf16x8 __attribute__((ext_vector_type(8)));
typedef float  f32x4  __attribute__((ext_vector_type(4)));

// top-3 insert via med3: 3 independent ops; t0 >= t1 >= t2 invariant.
#define TOP3_INS(v, t0, t1, t2) do {                              \
    float _v = (v);                                               \
    float _n0 = fmaxf(_v, (t0));                                  \
    float _n1 = __builtin_amdgcn_fmed3f(_v, (t0), (t1));          \
    float _n2 = __builtin_amdgcn_fmed3f(_v, (t1), (t2));          \
    (t0) = _n0; (t1) = _n1; (t2) = _n2; } while (0)

// Merge two SORTED triples (u desc, v desc) -> u = top-3 of union. 6 ops.
// Field-validated rounds 9-14 (absmax 0).
#define TRIPLE_MERGE(u0, u1, u2, v0, v1, v2) do {                 \
    float _A = fminf((u0), (v0));                                 \
    float _B = fmaxf((u1), (v1));                                 \
    float _E = fmaxf((u2), (v2));                                 \
    float _m0 = fmaxf((u0), (v0));                                \
    float _m1 = __builtin_amdgcn_fmed3f((u0), (v0), _B);          \
    float _m2 = __builtin_amdgcn_fmed3f(_A, _B, _E);              \
    (u0) = _m0; (u1) = _m1; (u2) = _m2; } while (0)

typedef __attribute__((address_space(1))) const void g_void;
typedef __attribute__((address_space(3))) void l_void;
__device__ __forceinline__ void gload_lds16(const void* g, void* l) {
    __builtin_amdgcn_global_load_lds((g_void*)g, (l_void*)l, 16, 0, 0);
}

#define MFMA16(A, B, C) __builtin_amdgcn_mfma_f32_16x16x32_bf16((A), (B), (C), 0, 0, 0)

// ---------------------------------------------------------------------------
// Kernel 1: L2-normalize all rows (support + anchor) into row-major bf16.
// Support -> sb with per-class row stride PER_CLS_PAD; pad rows zero-filled.
// ---------------------------------------------------------------------------
__global__ __launch_bounds__(256) void norm_rows_kernel(
    const float* __restrict__ anchor, const float* __restrict__ support,
    __bf16* __restrict__ qb, __bf16* __restrict__ sb) {
    int r = blockIdx.x * 256 + threadIdx.x;
    const int total_main = MSUP + NROWS;
    if (r >= total_main) {
        int i = r - total_main;                    // pad-row zero fill
        if (i < CLASSES * NPAD) {
            int cls = i / NPAD, ix = PER_CLS + i % NPAD;
            __bf16* op = sb + ((size_t)cls * PER_CLS_PAD + ix) * C_DIM;
            bf16x8 z = {};
            #pragma unroll
            for (int c0 = 0; c0 < C_DIM; c0 += 8) *(bf16x8*)(op + c0) = z;
        }
        return;
    }
    bool isSup = r < MSUP;
    int rc = isSup ? r : r - MSUP;
    const float* in = isSup ? support : anchor;
    int img = rc / HW, p = rc % HW;
    const float* base = in + (size_t)img * C_DIM * HW + p;
    float q[C_DIM];
    float ss = 0.f;
    #pragma unroll
    for (int c = 0; c < C_DIM; ++c) { q[c] = base[c * HW]; ss += q[c] * q[c]; }
    float sc = rsqrtf(ss);
    __bf16* op;
    if (isSup) {
        int cls = rc / PER_CLS, ix = rc - cls * PER_CLS;
        op = sb + ((size_t)cls * PER_CLS_PAD + ix) * C_DIM;
    } else {
        op = qb + (size_t)rc * C_DIM;
    }
    #pragma unroll
    for (int c0 = 0; c0 < C_DIM; c0 += 8) {
        bf16x8 v;
        #pragma unroll
        for (int j = 0; j < 8; ++j) v[j] = (__bf16)(q[c0 + j] * sc);
        *(bf16x8*)(op + c0) = v;
    }
}

// ---------------------------------------------------------------------------
// Fully-unrolled GEMM+top3 over one column-quarter (QNT tiles of 32 cols).
// CONTIGUOUS staging: wave w copies the contiguous 1KB chunk [w*1024,+1024)
// of each 4KB row-major tile into LDS (lane-permuted source, same cache
// lines -> fully coalesced). XOR swizzle (both-sides, rule #21):
//   LDS[row*128 + (y ^ ((row&7)<<4))] = G[row*128 + y]
// so the B-fragment ds_read at row*128 + ((h*64+kg*16) ^ ((lr&7)<<4))
// returns G[row*128 + h*64+kg*16] and spreads the stride-128 column read
// uniformly across all bank groups.
// 3 buffers, stage 2 ahead, counted vmcnt(1); decoupled MFMA/TOP3 streams.
// TAIL=true: last tile is class cols 2176-2207 (s=0 full, s=1 iff lr<13).
// ---------------------------------------------------------------------------
template<int QNT, bool TAIL>
__device__ __forceinline__ void gemm_quarter(
    const char* stage_src,        // qbase + w*1024 + per-lane swizzled offset
    char* smem_base,              // 3 x 4KB LDS buffers
    const char* pB,               // smem_base + lr*128 (per-lane read base)
    int xoff0, int xoff1,         // swizzled byte offsets for h=0 / h=1
    int stage_dst_off,            // w*1024 (wave's chunk in each buffer)
    int lane, int lr,
    const bf16x8 a0[2], const bf16x8 a1[2],
    float t0[2][4], float t1[2][4], float t2[2][4]) {

    auto stage = [&](int buf, int tt) {
        gload_lds16(stage_src + tt * TILE_BYTES,
                    smem_base + buf * 4096 + stage_dst_off);
    };
    const f32x4 z = {0.f, 0.f, 0.f, 0.f};

    stage(0, 0);
    stage(1, 1);
    #pragma unroll
    for (int tt = 0; tt < QNT; ++tt) {
        if (tt < QNT - 1) asm volatile("s_waitcnt vmcnt(1)" ::: "memory");
        else              asm volatile("s_waitcnt vmcnt(0)" ::: "memory");
        __builtin_amdgcn_s_barrier();
        if (tt + 2 < QNT) stage((tt + 2) % 3, tt + 2);
        const int buf = tt % 3;
        const bool tail = TAIL && (tt == QNT - 1);
        const char* pb = pB + buf * 4096;
        bf16x8 b0 = *(const bf16x8*)(pb + xoff0);          // s=0, k-half 0
        bf16x8 b1 = *(const bf16x8*)(pb + xoff1);          // s=0, k-half 1
        bf16x8 b2 = *(const bf16x8*)(pb + 2048 + xoff0);   // s=1, k-half 0
        bf16x8 b3 = *(const bf16x8*)(pb + 2048 + xoff1);   // s=1, k-half 1
        f32x4 acc0, acc1, acc2, acc3;
        __builtin_amdgcn_s_setprio(1);
        acc0 = MFMA16(a0[0], b0, z); acc0 = MFMA16(a1[0], b1, acc0);
        acc1 = MFMA16(a0[1], b0, z); acc1 = MFMA16(a1[1], b1, acc1);
        acc2 = MFMA16(a0[0], b2, z); acc2 = MFMA16(a1[0], b3, acc2);
        acc3 = MFMA16(a0[1], b2, z); acc3 = MFMA16(a1[1], b3, acc3);
        __builtin_amdgcn_s_setprio(0);
        if (!tail) {
            #pragma unroll
            for (int j = 0; j < 4; ++j) {
                TOP3_INS(acc0[j], t0[0][j], t1[0][j], t2[0][j]);
                TOP3_INS(acc1[j], t0[1][j], t1[1][j], t2[1][j]);
                TOP3_INS(acc2[j], t0[0][j], t1[0][j], t2[0][j]);
                TOP3_INS(acc3[j], t0[1][j], t1[1][j], t2[1][j]);
            }
        } else {
            // class tile 68: s=0 (acc0/acc1) full; s=1 (acc2/acc3) iff lr<13
            bool valid = lr < 13;     // SELECT mask: pad rows stay out
            #pragma unroll
            for (int j = 0; j < 4; ++j) {
                TOP3_INS(acc0[j], t0[0][j], t1[0][j], t2[0][j]);
                TOP3_INS(acc1[j], t0[1][j], t1[1][j], t2[1][j]);
                float v2 = valid ? acc2[j] : NEG_INF;
                float v3 = valid ? acc3[j] : NEG_INF;
                TOP3_INS(v2, t0[0][j], t1[0][j], t2[0][j]);
                TOP3_INS(v3, t0[1][j], t1[1][j], t2[1][j]);
            }
        }
    }
}

// ---------------------------------------------------------------------------
// Kernel 2: MFMA GEMM + partial top-3 per (row, class, quarter).
// Grid (111, 20), block 256 = 4 waves; wave owns 32 rows (M_rep=2).
// LDS 12 KB (3 x 4KB); contiguous staging + XOR-swizzled LDS reads.
// A/B frag: row/col = lane&15, k = (lane>>4)*8+[0..7].
// C/D: col = lane&15, row = (lane>>4)*4 + reg.   (validated rounds 2-14)
// ---------------------------------------------------------------------------
__global__ __launch_bounds__(256, 4) void knn_mfma_kernel(
    const __bf16* __restrict__ qb, const __bf16* __restrict__ sb,
    float* __restrict__ part) {
    __shared__ char smem[3][4096];   // 12 KB

    int lane = threadIdx.x & 63;
    int w    = threadIdx.x >> 6;           // 0..3
    int lr   = lane & 15;
    int kg   = lane >> 4;
    int cls  = blockIdx.y >> 2;
    int q    = blockIdx.y & 3;
    int rowbase = blockIdx.x * ROWS_PER_BLK + w * 32;

    bf16x8 a0[2], a1[2];
    #pragma unroll
    for (int r = 0; r < 2; ++r) {
        int arow = rowbase + r * 16 + lr;
        int arc  = arow < NROWS ? arow : NROWS - 1;
        const bf16x8* qrow = (const bf16x8*)(qb + (size_t)arc * C_DIM);
        a0[r] = qrow[kg];
        a1[r] = qrow[4 + kg];
    }

    float t0[2][4], t1[2][4], t2[2][4];
    #pragma unroll
    for (int r = 0; r < 2; ++r)
        #pragma unroll
        for (int j = 0; j < 4; ++j) {
            t0[r][j] = NEG_INF; t1[r][j] = NEG_INF; t2[r][j] = NEG_INF;
        }

    // ---- contiguous-stage addressing -------------------------------------
    // dest (linear, required by gload_lds): buf_base + w*1024 + lane*16
    //   -> LDS row = 8w + (lane>>3), y = (lane&7)*16
    // source must hold G[row*128 + (y ^ ((row&7)<<4))]:
    int srow = lane >> 3;                       // 0..7 (row within chunk)
    int sgrn = (lane & 7) ^ (srow & 7);         // XOR-permuted granule
    int srcSwz = srow * 128 + sgrn * 16;        // contiguous 1KB footprint
    const char* qbase = (const char*)sb
        + (size_t)cls * PER_CLS_PAD * ROW_BYTES
        + (size_t)q * TILES_PER_Q * TILE_BYTES;
    const char* stage_src = qbase + w * 1024 + srcSwz;
    // ---- swizzled B-fragment read addressing -----------------------------
    // byte chunk for (h,kg) = h*64 + kg*16; XOR mask = (lr&7)<<4
    int xoff0 = (((lr & 7) ^ kg) << 4);         // h=0
    int xoff1 = xoff0 ^ 0x40;                   // h=1 (flip bit 6)
    const char* pB = (const char*)smem + lr * 128;

    if (q == 3)   // tiles 54..68 valid (69..71 all-pad skipped), tail masked
        gemm_quarter<15, true >(stage_src, (char*)smem, pB, xoff0, xoff1,
                                w * 1024, lane, lr, a0, a1, t0, t1, t2);
    else
        gemm_quarter<18, false>(stage_src, (char*)smem, pB, xoff0, xoff1,
                                w * 1024, lane, lr, a0, a1, t0, t1, t2);

    // Merge top-3 across the 16 column-lanes per row (sorted-triple butterfly)
    #pragma unroll
    for (int r = 0; r < 2; ++r) {
        #pragma unroll
        for (int j = 0; j < 4; ++j) {
            float u0 = t0[r][j], u1 = t1[r][j], u2 = t2[r][j];
            #pragma unroll
            for (int off = 1; off < 16; off <<= 1) {
                float v0 = __shfl_xor(u0, off, 64);
                float v1 = __shfl_xor(u1, off, 64);
                float v2 = __shfl_xor(u2, off, 64);
                TRIPLE_MERGE(u0, u1, u2, v0, v1, v2);
            }
            int row = rowbase + r * 16 + kg * 4 + j;
            if (lr == 0 && row < NROWS) {
                float* pp = part +
                    ((size_t)(row * CLASSES + cls) * QUARTERS + q) * 3;
                pp[0] = u0; pp[1] = u1; pp[2] = u2;
            }
        }
    }
}

// ---------------------------------------------------------------------------
// Kernel 3: merge quarter partial top-3s, sigmoid, reduce over 441 locations.
// ---------------------------------------------------------------------------
__global__ __launch_bounds__(64) void merge_reduce_kernel(
    const float* __restrict__ part, float* __restrict__ out) {
    int bl = blockIdx.x;
    int b = bl / CLASSES;
    int l = bl % CLASSES;
    int lane = threadIdx.x;
    float acc = 0.f;
    for (int p = lane; p < HW; p += 64) {
        int row = b * HW + p;
        const float* pp = part + (size_t)(row * CLASSES + l) * (QUARTERS * 3);
        float u0 = pp[0], u1 = pp[1], u2 = pp[2];
        TRIPLE_MERGE(u0, u1, u2, pp[3], pp[4],  pp[5]);
        TRIPLE_MERGE(u0, u1, u2, pp[6], pp[7],  pp[8]);
        TRIPLE_MERGE(u0, u1, u2, pp[9], pp[10], pp[11]);
        acc += 1.f / (1.f + __expf(-u0))
             + 1.f / (1.f + __expf(-u1))
             + 1.f / (1.f + __expf(-u2));
    }
    #pragma unroll
    for (int off = 32; off; off >>= 1) acc += __shfl_xor(acc, off, 64);
    if (lane == 0) out[bl] = acc;
}

// ---------------------------------------------------------------------------
extern "C" void kernel_launch(void* const* d_in, const int* in_sizes, int n_in,
                              void* d_out, int out_size, void* d_ws, size_t ws_size,
                              hipStream_t stream) {
    const float* anchor  = (const float*)d_in[0];
    const float* support = (const float*)d_in[1];
    // d_in[2]=av_num(1), d_in[3]=sav_num(1) -- fixed by setup, ignored.

    // ws: sb bf16[5*2304*64] | qb bf16[NROWS*64] | part f32[NROWS*5*4*3]
    __bf16* sb = (__bf16*)d_ws;
    __bf16* qb = sb + (size_t)CLASSES * PER_CLS_PAD * C_DIM;
    float* part = (float*)(qb + (size_t)NROWS * C_DIM);

    {
        int total = MSUP + NROWS + CLASSES * NPAD;
        dim3 g((total + 255) / 256);
        norm_rows_kernel<<<g, 256, 0, stream>>>(anchor, support, qb, sb);
    }
    {
        dim3 g(NBLK_X, CLASSES * QUARTERS);
        knn_mfma_kernel<<<g, 256, 0, stream>>>(qb, sb, part);
    }
    {
        dim3 gm(B_ANCH * CLASSES);
        merge_reduce_kernel<<<gm, 64, 0, stream>>>(part, (float*)d_out);
    }
}